// Round 11
// baseline (63.295 us; speedup 1.0000x reference)
//
#include <hip/hip_runtime.h>

#define B_ 16
#define M_ 200
#define S_ 32
#define C_ 2048
#define V_ 32000
#define D_ 128
#define HOPS_ 3

// ---------------------------------------------------------------------------
// K1: story bags grid-wide (R2-verified core). 32 lanes per bag, float4 rows.
//   m[b,i,:] = sum_s embA[stories[b,i,s],:]   (3200 bags, 400 blocks)
// ---------------------------------------------------------------------------
__global__ void k_embed(const int* __restrict__ stories,
                        const float* __restrict__ embA, float* __restrict__ m) {
    int lane = threadIdx.x & 31;
    int sent = (blockIdx.x * 256 + threadIdx.x) >> 5;   // < 3200 exactly
    const int* idx = stories + sent * S_;
    float* dst = m + sent * D_;
    float4 acc = {0.f, 0.f, 0.f, 0.f};
#pragma unroll 8
    for (int s = 0; s < S_; ++s) {
        const float4* row = (const float4*)(embA + (size_t)idx[s] * D_);
        float4 a = row[lane];
        acc.x += a.x; acc.y += a.y; acc.z += a.z; acc.w += a.w;
    }
    ((float4*)dst)[lane] = acc;
}

// ---------------------------------------------------------------------------
// K2: hops. One 1024-thread block per batch; m[b] staged into LDS (102.4 KB);
// u0 computed in-block from query (R7-verified); 3 hops from LDS.
// ---------------------------------------------------------------------------
__global__ void __launch_bounds__(1024) k_hops(
        const float* __restrict__ m, const int* __restrict__ query,
        const float* __restrict__ embA, const float* __restrict__ Hw,
        const float* __restrict__ Hb, float* __restrict__ uF) {
    const int b = blockIdx.x;
    const int t = threadIdx.x;
    const int lane = t & 63;
    const int wave = t >> 6;                 // 16 waves

    __shared__ float sm[M_][D_];             // 102.4 KB
    __shared__ float su[D_];
    __shared__ float sattn[M_];
    __shared__ float sred[16 * D_];
    __shared__ float smx, ssum;

    {   // stage m[b] -> LDS, coalesced float4
        const float4* src = (const float4*)(m + (size_t)b * M_ * D_);
        float4* dst = (float4*)sm;
        for (int j = t; j < M_ * D_ / 4; j += 1024) dst[j] = src[j];
    }
    // u0[d] = sum_s embA[query[b,s], d]   (128 threads, coalesced rows)
    if (t < D_) {
        float a = 0.f;
#pragma unroll 8
        for (int s = 0; s < S_; ++s) a += embA[(size_t)query[b * S_ + s] * D_ + t];
        su[t] = a;
    }
    __syncthreads();

    for (int hop = 0; hop < HOPS_; ++hop) {
        // scores: attn[i] = sm[i,:] . su   (one row per wave, shfl reduce)
        float2 uu = ((const float2*)su)[lane];
        for (int i = wave; i < M_; i += 16) {
            float2 mv = ((const float2*)sm[i])[lane];
            float p = mv.x * uu.x + mv.y * uu.y;
#pragma unroll
            for (int o = 32; o; o >>= 1) p += __shfl_xor(p, o);
            if (lane == 0) sattn[i] = p;
        }
        __syncthreads();
        // softmax max/sum by wave 0
        if (wave == 0) {
            float mx = -3.0e38f;
            for (int i = lane; i < M_; i += 64) mx = fmaxf(mx, sattn[i]);
#pragma unroll
            for (int o = 32; o; o >>= 1) mx = fmaxf(mx, __shfl_xor(mx, o));
            float sm_ = 0.f;
            for (int i = lane; i < M_; i += 64) sm_ += expf(sattn[i] - mx);
#pragma unroll
            for (int o = 32; o; o >>= 1) sm_ += __shfl_xor(sm_, o);
            if (lane == 0) { smx = mx; ssum = sm_; }
        }
        __syncthreads();
        if (t < M_) sattn[t] = expf(sattn[t] - smx) * (1.f / ssum);
        __syncthreads();
        // o[d] = sum_i attn[i]*sm[i][d]  (per-wave partials)
        float2 oacc = {0.f, 0.f};
        for (int i = wave; i < M_; i += 16) {
            float a = sattn[i];
            float2 mv = ((const float2*)sm[i])[lane];
            oacc.x += a * mv.x; oacc.y += a * mv.y;
        }
        ((float2*)sred)[wave * 64 + lane] = oacc;
        __syncthreads();
        // u_new[d] = Hb[d] + o[d] + sum_k Hw[d,k]*su[k]   (8 lanes per d)
        int d  = t >> 3;
        int k8 = t & 7;
        float tot = sred[k8 * D_ + d] + sred[(k8 + 8) * D_ + d];
        for (int k = k8; k < D_; k += 8) tot += Hw[d * D_ + k] * su[k];
#pragma unroll
        for (int o = 1; o < 8; o <<= 1) tot += __shfl_xor(tot, o);
        float un = Hb[d] + tot;
        __syncthreads();
        if (k8 == 0) su[d] = un;
        __syncthreads();
    }
    if (t < D_) uF[b * D_ + t] = su[t];
}

// ---------------------------------------------------------------------------
// K3: P[v,b] = dot(uF[b,:], embW[v,:]). Thread = (v-pair, quarter q):
// streams 2 embW rows once; each padded-LDS u read feeds FMAs for BOTH rows
// (halves ds_read count vs R10). 4-lane shfl butterfly; coalesced stores.
// ---------------------------------------------------------------------------
__global__ void __launch_bounds__(256) k_pv(
        const float* __restrict__ uF, const float* __restrict__ embW,
        float* __restrict__ P) {
    const int t = threadIdx.x;
    const int gtid = blockIdx.x * 256 + t;
    const int p = gtid >> 2;                 // v-pair index, [0, 16000)
    const int q = t & 3;
    const int v0 = p * 2;

    __shared__ float4 su4[16 * 36];          // padded u: slot = b*36 + q*9 + j
    {
#pragma unroll
        for (int it = 0; it < 2; ++it) {
            int f = t + it * 256;            // float4 index into uF (512 total)
            int b = f >> 5, k = f & 31;
            su4[b * 36 + (k >> 3) * 9 + (k & 7)] = ((const float4*)uF)[f];
        }
    }
    __syncthreads();

    const float4* w0 = (const float4*)(embW + (size_t)v0 * D_) + q * 8;
    const float4* w1 = (const float4*)(embW + (size_t)(v0 + 1) * D_) + q * 8;
    float acc0[16], acc1[16];
#pragma unroll
    for (int b = 0; b < 16; ++b) { acc0[b] = 0.f; acc1[b] = 0.f; }
#pragma unroll
    for (int j = 0; j < 8; ++j) {
        float4 a0 = w0[j];
        float4 a1 = w1[j];
#pragma unroll
        for (int b = 0; b < 16; ++b) {
            float4 x = su4[b * 36 + q * 9 + j];
            acc0[b] += a0.x * x.x + a0.y * x.y + a0.z * x.z + a0.w * x.w;
            acc1[b] += a1.x * x.x + a1.y * x.y + a1.z * x.z + a1.w * x.w;
        }
    }
#pragma unroll
    for (int b = 0; b < 16; ++b) {
        acc0[b] += __shfl_xor(acc0[b], 1);
        acc0[b] += __shfl_xor(acc0[b], 2);
        acc1[b] += __shfl_xor(acc1[b], 1);
        acc1[b] += __shfl_xor(acc1[b], 2);
    }
    float4 o0, o1;
    o0.x = acc0[q * 4 + 0]; o0.y = acc0[q * 4 + 1];
    o0.z = acc0[q * 4 + 2]; o0.w = acc0[q * 4 + 3];
    o1.x = acc1[q * 4 + 0]; o1.y = acc1[q * 4 + 1];
    o1.z = acc1[q * 4 + 2]; o1.w = acc1[q * 4 + 3];
    ((float4*)(P + (size_t)v0 * B_))[q] = o0;
    ((float4*)(P + (size_t)(v0 + 1) * B_))[q] = o1;
}

// ---------------------------------------------------------------------------
// K4: logits[b,c] = sum_s P[cand[c,s],b] + sum_s P[E[b,c,s],b]
// 8 lanes per (b,c) (R8 phase-4 verbatim): 1024 blocks, shfl combine.
// ---------------------------------------------------------------------------
__global__ void k_logits(const int* __restrict__ cand, const int* __restrict__ E,
                         const float* __restrict__ P, float* __restrict__ out) {
    int g8 = blockIdx.x * 256 + threadIdx.x;  // (b*C + c)*8 + q
    int q = g8 & 7;
    int g = g8 >> 3;
    int c = g & (C_ - 1);
    int b = g >> 11;
    const int4* src;
    if (q < 4) src = (const int4*)(cand + c * S_ + q * 8);
    else       src = (const int4*)(E + (size_t)g * S_ + (q - 4) * 8);
    float acc = 0.f;
#pragma unroll
    for (int j = 0; j < 2; ++j) {
        int4 w = src[j];
        acc += P[w.x * B_ + b] + P[w.y * B_ + b] + P[w.z * B_ + b] + P[w.w * B_ + b];
    }
    acc += __shfl_xor(acc, 1);
    acc += __shfl_xor(acc, 2);
    acc += __shfl_xor(acc, 4);
    if (q == 0) out[g] = acc;
}

extern "C" void kernel_launch(void* const* d_in, const int* in_sizes, int n_in,
                              void* d_out, int out_size, void* d_ws, size_t ws_size,
                              hipStream_t stream) {
    const int*   stories = (const int*)d_in[0];
    const int*   query   = (const int*)d_in[1];
    const int*   E       = (const int*)d_in[2];
    const int*   cand    = (const int*)d_in[3];
    const float* embA    = (const float*)d_in[4];
    const float* embW    = (const float*)d_in[5];
    const float* Hw      = (const float*)d_in[6];
    const float* Hb      = (const float*)d_in[7];
    float* out = (float*)d_out;

    char* ws = (char*)d_ws;
    float* uF = (float*)ws;                                   //   8 KB
    float* m  = (float*)(ws + 8192);                          // 1.6 MB
    float* P  = (float*)(ws + 8192 + (size_t)B_ * M_ * D_ * 4);   // 2.0 MB

    hipLaunchKernelGGL(k_embed,  dim3(B_ * M_ * 32 / 256), dim3(256), 0, stream,
                       stories, embA, m);
    hipLaunchKernelGGL(k_hops,   dim3(B_), dim3(1024), 0, stream,
                       m, query, embA, Hw, Hb, uF);
    hipLaunchKernelGGL(k_pv,     dim3(V_ * 2 / 256), dim3(256), 0, stream, uF, embW, P);
    hipLaunchKernelGGL(k_logits, dim3((B_ * C_ * 8) / 256), dim3(256), 0, stream,
                       cand, E, P, out);
}

// Round 12
// 59.992 us; speedup vs baseline: 1.0551x; 1.0551x over previous
//
#include <hip/hip_runtime.h>

#define B_ 16
#define M_ 200
#define S_ 32
#define C_ 2048
#define V_ 32000
#define D_ 128
#define HOPS_ 3

// ---------------------------------------------------------------------------
// K1: embedding bags grid-wide (R2/R10-verified verbatim). 32 lanes per bag.
// ---------------------------------------------------------------------------
__global__ void k_embed(const int* __restrict__ stories, const int* __restrict__ query,
                        const float* __restrict__ embA,
                        float* __restrict__ m, float* __restrict__ u0) {
    int lane = threadIdx.x & 31;
    int sent = (blockIdx.x * 256 + threadIdx.x) >> 5;
    if (sent >= B_ * M_ + B_) return;
    const int* idx;
    float* dst;
    if (sent < B_ * M_) { idx = stories + sent * S_; dst = m + sent * D_; }
    else { int b = sent - B_ * M_; idx = query + b * S_; dst = u0 + b * D_; }
    float4 acc = {0.f, 0.f, 0.f, 0.f};
#pragma unroll 8
    for (int s = 0; s < S_; ++s) {
        const float4* row = (const float4*)(embA + (size_t)idx[s] * D_);
        float4 a = row[lane];
        acc.x += a.x; acc.y += a.y; acc.z += a.z; acc.w += a.w;
    }
    ((float4*)dst)[lane] = acc;
}

// ---------------------------------------------------------------------------
// K2: hops (R10-verified verbatim). One 1024-thread block per batch; m[b]
// staged into LDS (102.4 KB); 3 hops from LDS.
// ---------------------------------------------------------------------------
__global__ void __launch_bounds__(1024) k_hops(
        const float* __restrict__ m, const float* __restrict__ u0,
        const float* __restrict__ Hw, const float* __restrict__ Hb,
        float* __restrict__ uF) {
    const int b = blockIdx.x;
    const int t = threadIdx.x;
    const int lane = t & 63;
    const int wave = t >> 6;                 // 16 waves

    __shared__ float sm[M_][D_];             // 102.4 KB
    __shared__ float su[D_];
    __shared__ float sattn[M_];
    __shared__ float sred[16 * D_];
    __shared__ float smx, ssum;

    {   // stage m[b] -> LDS, coalesced float4
        const float4* src = (const float4*)(m + (size_t)b * M_ * D_);
        float4* dst = (float4*)sm;
        for (int j = t; j < M_ * D_ / 4; j += 1024) dst[j] = src[j];
    }
    if (t < D_) su[t] = u0[b * D_ + t];
    __syncthreads();

    for (int hop = 0; hop < HOPS_; ++hop) {
        float2 uu = ((const float2*)su)[lane];
        for (int i = wave; i < M_; i += 16) {
            float2 mv = ((const float2*)sm[i])[lane];
            float p = mv.x * uu.x + mv.y * uu.y;
#pragma unroll
            for (int o = 32; o; o >>= 1) p += __shfl_xor(p, o);
            if (lane == 0) sattn[i] = p;
        }
        __syncthreads();
        if (wave == 0) {
            float mx = -3.0e38f;
            for (int i = lane; i < M_; i += 64) mx = fmaxf(mx, sattn[i]);
#pragma unroll
            for (int o = 32; o; o >>= 1) mx = fmaxf(mx, __shfl_xor(mx, o));
            float sm_ = 0.f;
            for (int i = lane; i < M_; i += 64) sm_ += expf(sattn[i] - mx);
#pragma unroll
            for (int o = 32; o; o >>= 1) sm_ += __shfl_xor(sm_, o);
            if (lane == 0) { smx = mx; ssum = sm_; }
        }
        __syncthreads();
        if (t < M_) sattn[t] = expf(sattn[t] - smx) * (1.f / ssum);
        __syncthreads();
        float2 oacc = {0.f, 0.f};
        for (int i = wave; i < M_; i += 16) {
            float a = sattn[i];
            float2 mv = ((const float2*)sm[i])[lane];
            oacc.x += a * mv.x; oacc.y += a * mv.y;
        }
        ((float2*)sred)[wave * 64 + lane] = oacc;
        __syncthreads();
        int d  = t >> 3;
        int k8 = t & 7;
        float tot = sred[k8 * D_ + d] + sred[(k8 + 8) * D_ + d];
        for (int k = k8; k < D_; k += 8) tot += Hw[d * D_ + k] * su[k];
#pragma unroll
        for (int o = 1; o < 8; o <<= 1) tot += __shfl_xor(tot, o);
        float un = Hb[d] + tot;
        __syncthreads();
        if (k8 == 0) su[d] = un;
        __syncthreads();
    }
    if (t < D_) uF[b * D_ + t] = su[t];
}

// ---------------------------------------------------------------------------
// K3: P[v,b] (R10-verified verbatim). Thread = (v, quarter q): streams 128 B
// of embW once; acc[16] in VGPRs; bank-padded LDS u; 4-lane shfl butterfly.
// ---------------------------------------------------------------------------
__global__ void __launch_bounds__(256) k_pv(
        const float* __restrict__ uF, const float* __restrict__ embW,
        float* __restrict__ P) {
    const int t = threadIdx.x;
    const int gtid = blockIdx.x * 256 + t;
    const int v = gtid >> 2;
    const int q = t & 3;

    __shared__ float4 su4[16 * 36];          // padded u: slot = b*36 + q*9 + j
    {
#pragma unroll
        for (int it = 0; it < 2; ++it) {
            int f = t + it * 256;            // float4 index into uF (512 total)
            int b = f >> 5, k = f & 31;
            su4[b * 36 + (k >> 3) * 9 + (k & 7)] = ((const float4*)uF)[f];
        }
    }
    __syncthreads();

    const float4* w = (const float4*)(embW + (size_t)v * D_) + q * 8;
    float acc[16];
#pragma unroll
    for (int b = 0; b < 16; ++b) acc[b] = 0.f;
#pragma unroll
    for (int j = 0; j < 8; ++j) {
        float4 a = w[j];
#pragma unroll
        for (int b = 0; b < 16; ++b) {
            float4 x = su4[b * 36 + q * 9 + j];
            acc[b] += a.x * x.x + a.y * x.y + a.z * x.z + a.w * x.w;
        }
    }
#pragma unroll
    for (int b = 0; b < 16; ++b) {
        acc[b] += __shfl_xor(acc[b], 1);
        acc[b] += __shfl_xor(acc[b], 2);
    }
    float4 o;
    o.x = acc[q * 4 + 0]; o.y = acc[q * 4 + 1];
    o.z = acc[q * 4 + 2]; o.w = acc[q * 4 + 3];
    ((float4*)(P + (size_t)v * B_))[q] = o;
}

// ---------------------------------------------------------------------------
// K4: logits, 8 lanes per (b,c) (R8 phase-4 verified logic): q<4 -> cand
// quarters, q>=4 -> E quarters; 8-lane shfl butterfly; 1024 blocks.
// ---------------------------------------------------------------------------
__global__ void k_logits(const int* __restrict__ cand, const int* __restrict__ E,
                         const float* __restrict__ P, float* __restrict__ out) {
    int g8 = blockIdx.x * 256 + threadIdx.x;  // (b*C + c)*8 + q
    int q = g8 & 7;
    int g = g8 >> 3;
    int c = g & (C_ - 1);
    int b = g >> 11;
    const int4* src;
    if (q < 4) src = (const int4*)(cand + c * S_ + q * 8);
    else       src = (const int4*)(E + (size_t)g * S_ + (q - 4) * 8);
    float acc = 0.f;
#pragma unroll
    for (int j = 0; j < 2; ++j) {
        int4 w = src[j];
        acc += P[w.x * B_ + b] + P[w.y * B_ + b] + P[w.z * B_ + b] + P[w.w * B_ + b];
    }
    acc += __shfl_xor(acc, 1);
    acc += __shfl_xor(acc, 2);
    acc += __shfl_xor(acc, 4);
    if (q == 0) out[g] = acc;
}

extern "C" void kernel_launch(void* const* d_in, const int* in_sizes, int n_in,
                              void* d_out, int out_size, void* d_ws, size_t ws_size,
                              hipStream_t stream) {
    const int*   stories = (const int*)d_in[0];
    const int*   query   = (const int*)d_in[1];
    const int*   E       = (const int*)d_in[2];
    const int*   cand    = (const int*)d_in[3];
    const float* embA    = (const float*)d_in[4];
    const float* embW    = (const float*)d_in[5];
    const float* Hw      = (const float*)d_in[6];
    const float* Hb      = (const float*)d_in[7];
    float* out = (float*)d_out;

    char* ws = (char*)d_ws;
    float* u0 = (float*)ws;                                   //   8 KB
    float* uF = (float*)(ws + 8192);                          //   8 KB
    float* m  = (float*)(ws + 16384);                         // 1.6 MB
    float* P  = (float*)(ws + 16384 + (size_t)B_ * M_ * D_ * 4);  // 2.0 MB

    hipLaunchKernelGGL(k_embed,  dim3((B_ * M_ + B_) * 32 / 256), dim3(256), 0, stream,
                       stories, query, embA, m, u0);
    hipLaunchKernelGGL(k_hops,   dim3(B_), dim3(1024), 0, stream, m, u0, Hw, Hb, uF);
    hipLaunchKernelGGL(k_pv,     dim3(V_ * 4 / 256), dim3(256), 0, stream, uF, embW, P);
    hipLaunchKernelGGL(k_logits, dim3((B_ * C_ * 8) / 256), dim3(256), 0, stream,
                       cand, E, P, out);
}